// Round 12
// baseline (403.956 us; speedup 1.0000x reference)
//
#include <hip/hip_runtime.h>
#include <hip/hip_bf16.h>
#include <math.h>

#define B 8
#define N 10000
#define D 16
#define E 320000
#define EH 32
#define EOUT 30
#define NOUT 64
#define FEAT 35   // 2*D + 2 + 1
#define FILL_BLOCKS ((E + 255) / 256)      // 1250
#define PQ1K_BLOCKS ((B * N) / 16)         // 5000 (PQ at 1024 thr = 16 waves)

typedef short bf16x8 __attribute__((ext_vector_type(8)));
typedef float f32x4 __attribute__((ext_vector_type(4)));

// compiler-level memory fence (ordering across LDS phase boundaries)
#define LDS_FENCE() asm volatile("" ::: "memory")

// fast sigmoid: v_exp_f32 + v_rcp_f32 (no precise-division sequence)
__device__ __forceinline__ float sigmoidf_(float v) {
    return __builtin_amdgcn_rcpf(1.0f + __expf(-v));
}

__device__ __forceinline__ unsigned int pack_bf16_2(float a, float b) {
    unsigned ua = __float_as_uint(a), ub = __float_as_uint(b);
    ua = (ua + 0x7FFFu + ((ua >> 16) & 1u)) >> 16;
    ub = (ub + 0x7FFFu + ((ub >> 16) & 1u)) >> 16;
    return ua | (ub << 16);
}

__device__ __forceinline__ unsigned short bf16rn(float f) {
    unsigned u = __float_as_uint(f);
    u = (u + 0x7FFFu + ((u >> 16) & 1u)) >> 16;
    return (unsigned short)u;
}

// ---------------------------------------------------------------------------
// Stats + CSR degree counting (256 blocks, grid-stride).
// ---------------------------------------------------------------------------
__global__ void __launch_bounds__(256) stats_count_kernel(
    const float* __restrict__ ea, const int* __restrict__ eidx,
    float* __restrict__ stats, int* __restrict__ cnt)
{
    float s0 = 0.f, s1 = 0.f, q0 = 0.f, q1 = 0.f;
    for (int i = blockIdx.x * blockDim.x + threadIdx.x; i < E; i += gridDim.x * blockDim.x) {
        float2 v = *(const float2*)(ea + 2 * (size_t)i);
        s0 += v.x; q0 += v.x * v.x;
        s1 += v.y; q1 += v.y * v.y;
        atomicAdd(&cnt[eidx[E + i]], 1);      // tgt (in)
        atomicAdd(&cnt[N + eidx[i]], 1);      // src (out)
    }
    #pragma unroll
    for (int off = 32; off > 0; off >>= 1) {
        s0 += __shfl_down(s0, off);
        s1 += __shfl_down(s1, off);
        q0 += __shfl_down(q0, off);
        q1 += __shfl_down(q1, off);
    }
    if ((threadIdx.x & 63) == 0) {
        atomicAdd(&stats[0], s0);
        atomicAdd(&stats[1], s1);
        atomicAdd(&stats[2], q0);
        atomicAdd(&stats[3], q1);
    }
}

// ---------------------------------------------------------------------------
// Scan (block 0) + stats finalize + W2 fragments, FUSED with P/Q precompute
// (blocks 1..PQ1K_BLOCKS at 1024 threads = 16 waves each). PQ depends on
// nothing and is consumed only by edge; scan depends only on cnt — they
// overlap here. grid==1 -> scan only (fallback).
// ---------------------------------------------------------------------------
__global__ void __launch_bounds__(1024) scan_pq_kernel(
    const int* __restrict__ cnt_in, int* __restrict__ offs,
    int* __restrict__ cursor, float* __restrict__ stats,
    const float* __restrict__ W2, unsigned short* __restrict__ w2f,
    const float* __restrict__ x, const float* __restrict__ W1,
    const float* __restrict__ b1,
    unsigned short* __restrict__ Pb, unsigned short* __restrict__ Qb)
{
    if (blockIdx.x > 0) {
        // ---- P/Q precompute (16 waves per block) ----
        int wid = (blockIdx.x - 1) * 16 + (threadIdx.x >> 6);
        int lane = threadIdx.x & 63;
        if (wid >= B * N) return;
        int j = lane & 31;
        int half = lane >> 5;
        const float* xr = x + (size_t)wid * D;
        float acc = half ? b1[j] : 0.f;
        const float* Wb = W1 + (half ? D * EH : 0);
        #pragma unroll
        for (int d = 0; d < D; d++)
            acc = fmaf(xr[d], Wb[d * EH + j], acc);
        float accN = __shfl_down(acc, 1);   // neighbor col j+1 (same half)
        if (!(lane & 1)) {
            unsigned u = pack_bf16_2(acc, accN);
            unsigned short* dst = (half ? Qb : Pb) + (size_t)wid * EH + j;
            *(unsigned*)dst = u;            // j even -> 4B-aligned
        }
        return;
    }

    if (threadIdx.x == 0) {
        const float n = (float)E;
        float s0 = stats[0], s1 = stats[1], q0 = stats[2], q1 = stats[3];
        float v0 = (q0 - s0 * s0 / n) / (n - 1.0f);
        float v1 = (q1 - s1 * s1 / n) / (n - 1.0f);
        stats[4] = s0 / n;
        stats[5] = 1.0f / sqrtf(v0);
        stats[6] = s1 / n;
        stats[7] = 1.0f / sqrtf(v1);
    }
    if (threadIdx.x < 128) {
        int tl = threadIdx.x >> 6;        // output-col tile 0 / 1
        int ln = threadIdx.x & 63;
        int k0 = (ln >> 4) * 8;
        int col = tl * 16 + (ln & 15);
        unsigned short* hi = w2f + ((size_t)(tl * 2 + 0) * 64 + ln) * 8;
        unsigned short* lo = w2f + ((size_t)(tl * 2 + 1) * 64 + ln) * 8;
        #pragma unroll
        for (int j = 0; j < 8; j++) {
            float w = (col < EOUT) ? W2[(k0 + j) * EOUT + col] : 0.0f;
            unsigned u = __float_as_uint(w) & 0xFFFF0000u;
            float r = w - __uint_as_float(u);
            hi[j] = (unsigned short)(u >> 16);
            lo[j] = bf16rn(r);
        }
    }
    const int M = 2 * N;
    const int CH = 20;
    __shared__ int lds[1024];
    int t = threadIdx.x;
    int base = t * CH;
    int loc[CH];
    int s = 0;
    #pragma unroll
    for (int i = 0; i < CH; i++) {
        int idx = base + i;
        int v = (idx < M) ? cnt_in[idx] : 0;
        loc[i] = s;
        s += v;
    }
    lds[t] = s;
    __syncthreads();
    for (int off = 1; off < 1024; off <<= 1) {
        int v = (t >= off) ? lds[t - off] : 0;
        __syncthreads();
        lds[t] += v;
        __syncthreads();
    }
    int tbase = (t > 0) ? lds[t - 1] : 0;
    #pragma unroll
    for (int i = 0; i < CH; i++) {
        int idx = base + i;
        if (idx < M) {
            offs[idx] = tbase + loc[i];
            cursor[idx] = tbase + loc[i];
        }
    }
    if (t == 1023) offs[M] = lds[1023];
}

// ---------------------------------------------------------------------------
// CSR slot assignment. INVERTED vs lists: writes pos[e] = in-slot (in [0,E))
// and pos[E+e] = out-slot (in [E,2E)) — COALESCED writes (the old
// lists[p]=e scatter dirtied 41 MB of lines). Edge uses pos to place its
// output row; gather then streams slots in order.
// ---------------------------------------------------------------------------
__global__ void __launch_bounds__(256) fill_kernel(
    const int* __restrict__ eidx, int* __restrict__ cursor,
    int* __restrict__ pos)
{
    int e = blockIdx.x * 256 + threadIdx.x;
    if (e >= E) return;
    int p = atomicAdd(&cursor[eidx[E + e]], 1);   // in-slot of tgt
    pos[e] = p;
    int q = atomicAdd(&cursor[N + eidx[e]], 1);   // out-slot of src
    pos[E + e] = q;
}

// ---------------------------------------------------------------------------
// Edge MLP (round-9/11 verified math, UNCHANGED through the LDS transpose).
// Epilogue change: instead of one linear copy to an edge-ordered eBuf, each
// row is written to TWO slot-addressed rows of eBuf2 (slots pos[e], pos[E+e]).
// Scattered but full-64B-line writes (fire-and-forget); converts gather's
// random reads into streaming reads.
// ---------------------------------------------------------------------------
__global__ void __launch_bounds__(256) edge_mlp_kernel(
    const float* __restrict__ x, const int* __restrict__ eidx,
    const float* __restrict__ ea,
    const float* __restrict__ wind_mean, const float* __restrict__ wind_std,
    const float* __restrict__ W1, const float* __restrict__ b2,
    const float* __restrict__ stats,
    const unsigned short* __restrict__ Pb, const unsigned short* __restrict__ Qb,
    const unsigned short* __restrict__ w2f,
    unsigned short* __restrict__ eBuf2,
    const int* __restrict__ pos,
    int b0, int ebOff)
{
    __shared__ unsigned short hsh[4][64][64];  // 32 KB: wave-private slabs

    int t = blockIdx.x * 256 + threadIdx.x;   // < nb*E
    int bb = t / E;
    int e = t - bb * E;
    int b = b0 + bb;
    int wv = threadIdx.x >> 6;
    int lane = threadIdx.x & 63;

    int src = eidx[e];
    int tgt = eidx[E + e];

    const uint4* Pr = (const uint4*)(Pb + ((size_t)b * N + src) * EH);  // 64 B
    const uint4* Qr = (const uint4*)(Qb + ((size_t)b * N + tgt) * EH);  // 64 B

    float h[EH];
    #pragma unroll
    for (int i = 0; i < 4; i++) {
        uint4 p = Pr[i];
        uint4 q = Qr[i];
        unsigned pu[4] = {p.x, p.y, p.z, p.w};
        unsigned qu[4] = {q.x, q.y, q.z, q.w};
        #pragma unroll
        for (int k2 = 0; k2 < 4; k2++) {
            float pl = __uint_as_float(pu[k2] << 16);
            float ph = __uint_as_float(pu[k2] & 0xFFFF0000u);
            float ql = __uint_as_float(qu[k2] << 16);
            float qh = __uint_as_float(qu[k2] & 0xFFFF0000u);
            h[8 * i + 2 * k2 + 0] = pl + ql;
            h[8 * i + 2 * k2 + 1] = ph + qh;
        }
    }

    float2 eav = *(const float2*)(ea + 2 * (size_t)e);
    float dist = eav.x, cdir = eav.y;
    float f32v = (dist - stats[4]) * stats[5];
    float f33v = (cdir - stats[6]) * stats[7];

    float2 xw = *(const float2*)(x + ((size_t)b * N + src) * D + 14);
    float speed = xw.x * wind_std[0] + wind_mean[0];
    float sdir  = xw.y * wind_std[1] + wind_mean[1];
    float ew = fmaxf(3.0f * speed * __cosf(fabsf(cdir - sdir)) *
                     __builtin_amdgcn_rcpf(dist), 0.0f);

    const float* W1r32 = W1 + 32 * EH;
    const float* W1r33 = W1 + 33 * EH;
    const float* W1r34 = W1 + 34 * EH;
    #pragma unroll
    for (int j = 0; j < EH; j++) {
        float v = h[j];
        v = fmaf(f32v, W1r32[j], v);
        v = fmaf(f33v, W1r33[j], v);
        v = fmaf(ew,   W1r34[j], v);
        h[j] = sigmoidf_(v);
    }

    // --- stage h as bf16 RNE (hi only), chunk-swizzled ---
    unsigned short* myrow = &hsh[wv][lane][0];
    int lx = lane & 7;
    #pragma unroll
    for (int i = 0; i < 4; i++) {
        unsigned hw[4];
        #pragma unroll
        for (int p = 0; p < 4; p++)
            hw[p] = pack_bf16_2(h[8 * i + 2 * p], h[8 * i + 2 * p + 1]);
        *(uint4*)(myrow + ((i ^ lx) << 3)) = make_uint4(hw[0], hw[1], hw[2], hw[3]);
    }
    LDS_FENCE();

    // --- B fragments (L1-hot, 4KB shared by all waves) ---
    union { uint4 u; bf16x8 v; } bf[4];
    const uint4* wfp = (const uint4*)w2f;
    #pragma unroll
    for (int i = 0; i < 4; i++) bf[i].u = wfp[i * 64 + lane];
    // bf[0]=tile0 hi, bf[1]=tile0 lo, bf[2]=tile1 hi, bf[3]=tile1 lo

    int m  = lane & 15;
    int hr = lane >> 4;
    float bias0 = b2[m];
    float bias1 = (m < EOUT - 16) ? b2[16 + m] : 0.0f;

    f32x4 acc[4][2];
    #pragma unroll
    for (int g = 0; g < 4; g++) {
        f32x4 z0 = {bias0, bias0, bias0, bias0};
        f32x4 z1 = {bias1, bias1, bias1, bias1};
        acc[g][0] = z0;
        acc[g][1] = z1;
    }

    int mx = m & 7;
    #pragma unroll
    for (int g = 0; g < 4; g++) {
        const unsigned short* rp = &hsh[wv][g * 16 + m][0];
        bf16x8 Ah = *(const bf16x8*)(rp + ((hr ^ mx) << 3));
        acc[g][0] = __builtin_amdgcn_mfma_f32_16x16x32_bf16(Ah, bf[0].v, acc[g][0], 0, 0, 0);
        acc[g][1] = __builtin_amdgcn_mfma_f32_16x16x32_bf16(Ah, bf[2].v, acc[g][1], 0, 0, 0);
        acc[g][0] = __builtin_amdgcn_mfma_f32_16x16x32_bf16(Ah, bf[1].v, acc[g][0], 0, 0, 0);
        acc[g][1] = __builtin_amdgcn_mfma_f32_16x16x32_bf16(Ah, bf[3].v, acc[g][1], 0, 0, 0);
    }
    LDS_FENCE();

    // --- epilogue: transpose C via LDS (staging data now dead) ---
    unsigned short* wb = &hsh[wv][0][0];   // 64 rows x 64 ush
    int c0 = m >> 3;
    int c1 = 2 + (m >> 3);
    int mp = m & 7;
    #pragma unroll
    for (int g = 0; g < 4; g++) {
        #pragma unroll
        for (int j = 0; j < 4; j++) {
            int er  = g * 16 + hr * 4 + j;
            int swz = ((hr & 1) << 2) | j;         // er & 7
            float v0 = sigmoidf_(acc[g][0][j]);
            float v1 = sigmoidf_(acc[g][1][j]);
            wb[er * 64 + ((c0 ^ swz) << 3) + mp] = bf16rn(v0);
            wb[er * 64 + ((c1 ^ swz) << 3) + mp] =
                (m < 14) ? bf16rn(v1) : (unsigned short)0;
        }
    }
    LDS_FENCE();

    // --- slot-addressed copy LDS -> eBuf2: each row to its 2 CSR slots ---
    // Lane covers (row = i*16 + lane>>2, ush cols (lane&3)*8..+7); a row's
    // 4 lanes fill one full 64B line at each destination.
    int eWaveBase = e - lane;
    int rrow = lane >> 2;
    int rx   = rrow & 7;
    unsigned short* eb2 = eBuf2 + (size_t)(b - ebOff) * (2 * E) * EH;
    #pragma unroll
    for (int i = 0; i < 4; i++) {
        int row = i * 16 + rrow;
        uint4 v = *(const uint4*)(wb + row * 64 + (((lane & 3) ^ rx) << 3));
        int eg   = eWaveBase + row;
        int pin  = pos[eg];        // in [0, E)
        int pout = pos[E + eg];    // in [E, 2E)
        *(uint4*)(eb2 + (size_t)pin  * EH + (lane & 3) * 8) = v;
        *(uint4*)(eb2 + (size_t)pout * EH + (lane & 3) * 8) = v;
    }
}

// ---------------------------------------------------------------------------
// Gather + node MLP. One wave per (bb,node). STREAMING: a node's in-rows
// [offs[node],offs[node+1]) and out-rows [offs[N+node],offs[N+node+1]) are
// CONTIGUOUS in eBuf2 — 1KB coalesced per wave instruction, no lists
// indirection. Math identical to the round-6 verified version (eid == row).
// ---------------------------------------------------------------------------
__global__ void __launch_bounds__(256) gather_kernel(
    const unsigned short* __restrict__ eBuf2, const int* __restrict__ offs,
    const float* __restrict__ Wn,
    const float* __restrict__ bn, float* __restrict__ out,
    int b0, int nb, int ebOff)
{
    int wid = (blockIdx.x * blockDim.x + threadIdx.x) >> 6;
    int lane = threadIdx.x & 63;
    if (wid >= nb * N) return;
    int bb = wid / N;
    int node = wid - bb * N;
    int b = b0 + bb;

    int g = lane >> 2;       // row-group 0..15
    int c = lane & 3;        // uint4 index in row: covers cols 8c..8c+7
    const uint4* ebase = (const uint4*)(eBuf2 + (size_t)(b - ebOff) * (2 * E) * EH);

    float a0 = 0.f, a1 = 0.f, a2 = 0.f, a3 = 0.f;
    float a4 = 0.f, a5 = 0.f, a6 = 0.f, a7 = 0.f;

    // in-slots: add
    {
        int s = offs[node], e1 = offs[node + 1];
        for (int r = s; r < e1; r += 16) {
            int row = r + g;
            if (row < e1) {
                uint4 v = ebase[(size_t)row * 4 + c];
                a0 += __uint_as_float(v.x << 16);
                a1 += __uint_as_float(v.x & 0xFFFF0000u);
                a2 += __uint_as_float(v.y << 16);
                a3 += __uint_as_float(v.y & 0xFFFF0000u);
                a4 += __uint_as_float(v.z << 16);
                a5 += __uint_as_float(v.z & 0xFFFF0000u);
                a6 += __uint_as_float(v.w << 16);
                a7 += __uint_as_float(v.w & 0xFFFF0000u);
            }
        }
    }
    // out-slots: subtract
    {
        int s = offs[N + node], e1 = offs[N + node + 1];
        for (int r = s; r < e1; r += 16) {
            int row = r + g;
            if (row < e1) {
                uint4 v = ebase[(size_t)row * 4 + c];
                a0 -= __uint_as_float(v.x << 16);
                a1 -= __uint_as_float(v.x & 0xFFFF0000u);
                a2 -= __uint_as_float(v.y << 16);
                a3 -= __uint_as_float(v.y & 0xFFFF0000u);
                a4 -= __uint_as_float(v.z << 16);
                a5 -= __uint_as_float(v.z & 0xFFFF0000u);
                a6 -= __uint_as_float(v.w << 16);
                a7 -= __uint_as_float(v.w & 0xFFFF0000u);
            }
        }
    }

    // fold the 16 row-groups: lanes sharing (lane&3) end with full column sums
    #pragma unroll
    for (int off = 4; off <= 32; off <<= 1) {
        a0 += __shfl_xor(a0, off); a1 += __shfl_xor(a1, off);
        a2 += __shfl_xor(a2, off); a3 += __shfl_xor(a3, off);
        a4 += __shfl_xor(a4, off); a5 += __shfl_xor(a5, off);
        a6 += __shfl_xor(a6, off); a7 += __shfl_xor(a7, off);
    }

    // node layer: agg col k lives in slot (k&7) of lane (k>>3)
    float o = bn[lane];
    #pragma unroll
    for (int k = 0; k < EOUT; k++) {
        float av;
        switch (k & 7) {
            case 0:  av = a0; break;
            case 1:  av = a1; break;
            case 2:  av = a2; break;
            case 3:  av = a3; break;
            case 4:  av = a4; break;
            case 5:  av = a5; break;
            case 6:  av = a6; break;
            default: av = a7; break;
        }
        float ak = __shfl(av, k >> 3);
        o = fmaf(ak, Wn[k * NOUT + lane], o);
    }
    out[((size_t)b * N + node) * NOUT + lane] = sigmoidf_(o);
}

// ---------------------------------------------------------------------------
// Fallback (small ws): atomic path
// ---------------------------------------------------------------------------
__global__ void __launch_bounds__(256) edge_kernel_atomic(
    const float* __restrict__ x, const int* __restrict__ eidx,
    const float* __restrict__ ea,
    const float* __restrict__ wind_mean, const float* __restrict__ wind_std,
    const float* __restrict__ W1, const float* __restrict__ b1,
    const float* __restrict__ W2, const float* __restrict__ b2,
    const float* __restrict__ stats, float* __restrict__ agg)
{
    int t = blockIdx.x * blockDim.x + threadIdx.x;
    if (t >= B * E) return;
    int b = t / E;
    int e = t - b * E;
    int src = eidx[e];
    int tgt = eidx[E + e];
    const float* xs = x + ((size_t)b * N + src) * D;
    const float* xt = x + ((size_t)b * N + tgt) * D;
    float f[FEAT];
    #pragma unroll
    for (int i = 0; i < D; i++) f[i] = xs[i];
    #pragma unroll
    for (int i = 0; i < D; i++) f[D + i] = xt[i];
    float2 eav = *(const float2*)(ea + 2 * (size_t)e);
    f[32] = (eav.x - stats[4]) * stats[5];
    f[33] = (eav.y - stats[6]) * stats[7];
    float speed = f[14] * wind_std[0] + wind_mean[0];
    float sdir  = f[15] * wind_std[1] + wind_mean[1];
    f[34] = fmaxf(3.0f * speed * cosf(fabsf(eav.y - sdir)) / eav.x, 0.0f);
    float h[EH];
    #pragma unroll
    for (int j = 0; j < EH; j++) h[j] = b1[j];
    #pragma unroll
    for (int k = 0; k < FEAT; k++) {
        float fk = f[k];
        #pragma unroll
        for (int j = 0; j < EH; j++) h[j] = fmaf(fk, W1[k * EH + j], h[j]);
    }
    #pragma unroll
    for (int j = 0; j < EH; j++) h[j] = sigmoidf_(h[j]);
    float o[EOUT];
    #pragma unroll
    for (int j = 0; j < EOUT; j++) o[j] = b2[j];
    #pragma unroll
    for (int k = 0; k < EH; k++) {
        float hk = h[k];
        #pragma unroll
        for (int j = 0; j < EOUT; j++) o[j] = fmaf(hk, W2[k * EOUT + j], o[j]);
    }
    float* at = agg + ((size_t)b * N + tgt) * EOUT;
    float* as = agg + ((size_t)b * N + src) * EOUT;
    #pragma unroll
    for (int j = 0; j < EOUT; j++) {
        float v = sigmoidf_(o[j]);
        atomicAdd(at + j,  v);
        atomicAdd(as + j, -v);
    }
}

__global__ void __launch_bounds__(256) node_kernel_fallback(
    const float* __restrict__ agg, const float* __restrict__ Wn,
    const float* __restrict__ bn, float* __restrict__ out)
{
    int t = blockIdx.x * blockDim.x + threadIdx.x;
    if (t >= B * N * NOUT) return;
    int row = t >> 6;
    int j   = t & 63;
    const float* a = agg + (size_t)row * EOUT;
    float acc = bn[j];
    #pragma unroll
    for (int k = 0; k < EOUT; k++) acc = fmaf(a[k], Wn[k * NOUT + j], acc);
    out[t] = sigmoidf_(acc);
}

// ---------------------------------------------------------------------------
extern "C" void kernel_launch(void* const* d_in, const int* in_sizes, int n_in,
                              void* d_out, int out_size, void* d_ws, size_t ws_size,
                              hipStream_t stream) {
    const float* x         = (const float*)d_in[0];
    const int*   eidx      = (const int*)d_in[1];
    const float* ea        = (const float*)d_in[2];
    const float* wind_mean = (const float*)d_in[3];
    const float* wind_std  = (const float*)d_in[4];
    const float* W1        = (const float*)d_in[5];
    const float* b1        = (const float*)d_in[6];
    const float* W2        = (const float*)d_in[7];
    const float* b2        = (const float*)d_in[8];
    const float* Wn        = (const float*)d_in[9];
    const float* bn        = (const float*)d_in[10];
    float* out = (float*)d_out;

    char* ws = (char*)d_ws;
    // layout:
    //   stats [0,256) | w2f [256,4352) | offs [4352,84480) | cnt/cursor [84480,164608)
    //   pos [164608,2724608)
    //   P(bf16) [2724608,7844608) | Q(bf16) [7844608,12964608) | eBuf2 [12964608,...)
    float*          stats = (float*)(ws + 0);
    unsigned short* w2f   = (unsigned short*)(ws + 256);
    int*            offs  = (int*)(ws + 4352);
    int*            cnt   = (int*)(ws + 84480);
    int*            pos   = (int*)(ws + 164608);
    unsigned short* Pb    = (unsigned short*)(ws + 2724608);
    unsigned short* Qb    = (unsigned short*)(ws + 7844608);
    unsigned short* eBuf2 = (unsigned short*)(ws + 12964608);
    const size_t fixed = 12964608;
    const size_t perBatch2 = (size_t)(2 * E) * EH * sizeof(unsigned short); // 40,960,000

    if (ws_size >= fixed + perBatch2) {
        int chunk = (int)((ws_size - fixed) / perBatch2);
        if (chunk > 8) chunk = 8;

        hipMemsetAsync(ws, 0, 164608, stream);

        stats_count_kernel<<<256, 256, 0, stream>>>(ea, eidx, stats, cnt);
        scan_pq_kernel<<<1 + PQ1K_BLOCKS, 1024, 0, stream>>>(
            cnt, offs, cnt, stats, W2, w2f, x, W1, b1, Pb, Qb);
        fill_kernel<<<FILL_BLOCKS, 256, 0, stream>>>(eidx, cnt, pos);

        for (int b0 = 0; b0 < B; b0 += chunk) {
            int nb = B - b0; if (nb > chunk) nb = chunk;
            edge_mlp_kernel<<<nb * (E / 256), 256, 0, stream>>>(
                x, eidx, ea, wind_mean, wind_std, W1, b2, stats,
                Pb, Qb, w2f, eBuf2, pos, b0, /*ebOff=*/b0);
            gather_kernel<<<nb * (N * 64 / 256), 256, 0, stream>>>(
                eBuf2, offs, Wn, bn, out, b0, nb, /*ebOff=*/b0);
        }
    } else {
        float* agg = (float*)(ws + 164608);
        size_t zero_bytes = 164608 + (size_t)B * N * EOUT * sizeof(float);
        hipMemsetAsync(ws, 0, zero_bytes, stream);
        stats_count_kernel<<<256, 256, 0, stream>>>(ea, eidx, stats, cnt);
        scan_pq_kernel<<<1, 1024, 0, stream>>>(
            cnt, offs, cnt, stats, W2, w2f, x, W1, b1,
            (unsigned short*)(ws + 256), (unsigned short*)(ws + 256));  // grid=1: PQ unused
        int nwork = B * E;
        edge_kernel_atomic<<<(nwork + 255) / 256, 256, 0, stream>>>(
            x, eidx, ea, wind_mean, wind_std, W1, b1, W2, b2, stats, agg);
        int nout_elems = B * N * NOUT;
        node_kernel_fallback<<<(nout_elems + 255) / 256, 256, 0, stream>>>(
            agg, Wn, bn, out);
    }
}

// Round 14
// 353.849 us; speedup vs baseline: 1.1416x; 1.1416x over previous
//
#include <hip/hip_runtime.h>
#include <hip/hip_bf16.h>
#include <math.h>

#define B 8
#define N 10000
#define D 16
#define E 320000
#define EH 32
#define EOUT 30
#define NOUT 64
#define FEAT 35   // 2*D + 2 + 1
#define FILL_BLOCKS ((E + 255) / 256)      // 1250
#define PQ1K_BLOCKS ((B * N) / 16)         // 5000 (PQ at 1024 thr = 16 waves)

typedef short bf16x8 __attribute__((ext_vector_type(8)));
typedef float f32x4 __attribute__((ext_vector_type(4)));

// compiler-level memory fence (ordering across LDS phase boundaries)
#define LDS_FENCE() asm volatile("" ::: "memory")

// fast sigmoid: v_exp_f32 + v_rcp_f32 (no precise-division sequence)
__device__ __forceinline__ float sigmoidf_(float v) {
    return __builtin_amdgcn_rcpf(1.0f + __expf(-v));
}

__device__ __forceinline__ unsigned int pack_bf16_2(float a, float b) {
    unsigned ua = __float_as_uint(a), ub = __float_as_uint(b);
    ua = (ua + 0x7FFFu + ((ua >> 16) & 1u)) >> 16;
    ub = (ub + 0x7FFFu + ((ub >> 16) & 1u)) >> 16;
    return ua | (ub << 16);
}

__device__ __forceinline__ unsigned short bf16rn(float f) {
    unsigned u = __float_as_uint(f);
    u = (u + 0x7FFFu + ((u >> 16) & 1u)) >> 16;
    return (unsigned short)u;
}

// ---------------------------------------------------------------------------
// Stats + CSR degree counting (256 blocks, grid-stride).
// ---------------------------------------------------------------------------
__global__ void __launch_bounds__(256) stats_count_kernel(
    const float* __restrict__ ea, const int* __restrict__ eidx,
    float* __restrict__ stats, int* __restrict__ cnt)
{
    float s0 = 0.f, s1 = 0.f, q0 = 0.f, q1 = 0.f;
    for (int i = blockIdx.x * blockDim.x + threadIdx.x; i < E; i += gridDim.x * blockDim.x) {
        float2 v = *(const float2*)(ea + 2 * (size_t)i);
        s0 += v.x; q0 += v.x * v.x;
        s1 += v.y; q1 += v.y * v.y;
        atomicAdd(&cnt[eidx[E + i]], 1);      // tgt (in)
        atomicAdd(&cnt[N + eidx[i]], 1);      // src (out)
    }
    #pragma unroll
    for (int off = 32; off > 0; off >>= 1) {
        s0 += __shfl_down(s0, off);
        s1 += __shfl_down(s1, off);
        q0 += __shfl_down(q0, off);
        q1 += __shfl_down(q1, off);
    }
    if ((threadIdx.x & 63) == 0) {
        atomicAdd(&stats[0], s0);
        atomicAdd(&stats[1], s1);
        atomicAdd(&stats[2], q0);
        atomicAdd(&stats[3], q1);
    }
}

// ---------------------------------------------------------------------------
// Scan (block 0) + stats finalize + W2 fragments, FUSED with P/Q precompute
// (blocks 1..PQ1K_BLOCKS at 1024 threads = 16 waves each). PQ depends on
// nothing and is consumed only by edge; scan depends only on cnt — they
// overlap here instead of running serially (round-10 measured ~-19 us).
// grid==1 -> scan only (fallback).
// ---------------------------------------------------------------------------
__global__ void __launch_bounds__(1024) scan_pq_kernel(
    const int* __restrict__ cnt_in, int* __restrict__ offs,
    int* __restrict__ cursor, float* __restrict__ stats,
    const float* __restrict__ W2, unsigned short* __restrict__ w2f,
    const float* __restrict__ x, const float* __restrict__ W1,
    const float* __restrict__ b1,
    unsigned short* __restrict__ Pb, unsigned short* __restrict__ Qb)
{
    if (blockIdx.x > 0) {
        // ---- P/Q precompute (16 waves per block) ----
        int wid = (blockIdx.x - 1) * 16 + (threadIdx.x >> 6);
        int lane = threadIdx.x & 63;
        if (wid >= B * N) return;
        int j = lane & 31;
        int half = lane >> 5;
        const float* xr = x + (size_t)wid * D;
        float acc = half ? b1[j] : 0.f;
        const float* Wb = W1 + (half ? D * EH : 0);
        #pragma unroll
        for (int d = 0; d < D; d++)
            acc = fmaf(xr[d], Wb[d * EH + j], acc);
        float accN = __shfl_down(acc, 1);   // neighbor col j+1 (same half)
        if (!(lane & 1)) {
            unsigned u = pack_bf16_2(acc, accN);
            unsigned short* dst = (half ? Qb : Pb) + (size_t)wid * EH + j;
            *(unsigned*)dst = u;            // j even -> 4B-aligned
        }
        return;
    }

    if (threadIdx.x == 0) {
        const float n = (float)E;
        float s0 = stats[0], s1 = stats[1], q0 = stats[2], q1 = stats[3];
        float v0 = (q0 - s0 * s0 / n) / (n - 1.0f);
        float v1 = (q1 - s1 * s1 / n) / (n - 1.0f);
        stats[4] = s0 / n;
        stats[5] = 1.0f / sqrtf(v0);
        stats[6] = s1 / n;
        stats[7] = 1.0f / sqrtf(v1);
    }
    if (threadIdx.x < 128) {
        int tl = threadIdx.x >> 6;        // output-col tile 0 / 1
        int ln = threadIdx.x & 63;
        int k0 = (ln >> 4) * 8;
        int col = tl * 16 + (ln & 15);
        unsigned short* hi = w2f + ((size_t)(tl * 2 + 0) * 64 + ln) * 8;
        unsigned short* lo = w2f + ((size_t)(tl * 2 + 1) * 64 + ln) * 8;
        #pragma unroll
        for (int j = 0; j < 8; j++) {
            float w = (col < EOUT) ? W2[(k0 + j) * EOUT + col] : 0.0f;
            unsigned u = __float_as_uint(w) & 0xFFFF0000u;
            float r = w - __uint_as_float(u);
            hi[j] = (unsigned short)(u >> 16);
            lo[j] = bf16rn(r);
        }
    }
    const int M = 2 * N;
    const int CH = 20;
    __shared__ int lds[1024];
    int t = threadIdx.x;
    int base = t * CH;
    int loc[CH];
    int s = 0;
    #pragma unroll
    for (int i = 0; i < CH; i++) {
        int idx = base + i;
        int v = (idx < M) ? cnt_in[idx] : 0;
        loc[i] = s;
        s += v;
    }
    lds[t] = s;
    __syncthreads();
    for (int off = 1; off < 1024; off <<= 1) {
        int v = (t >= off) ? lds[t - off] : 0;
        __syncthreads();
        lds[t] += v;
        __syncthreads();
    }
    int tbase = (t > 0) ? lds[t - 1] : 0;
    #pragma unroll
    for (int i = 0; i < CH; i++) {
        int idx = base + i;
        if (idx < M) {
            offs[idx] = tbase + loc[i];
            cursor[idx] = tbase + loc[i];
        }
    }
    if (t == 1023) offs[M] = lds[1023];
}

// ---------------------------------------------------------------------------
// Edge MLP + CSR-lists fill fused, INTERLEAVED (round-9 verified): one fill
// block every `period` blocks so fill's atomic-latency work overlaps edge
// compute throughout the dispatch. Edge math byte-identical to round-9.
// ---------------------------------------------------------------------------
__global__ void __launch_bounds__(256) edge_mlp_kernel(
    const float* __restrict__ x, const int* __restrict__ eidx,
    const float* __restrict__ ea,
    const float* __restrict__ wind_mean, const float* __restrict__ wind_std,
    const float* __restrict__ W1, const float* __restrict__ b2,
    const float* __restrict__ stats,
    const unsigned short* __restrict__ Pb, const unsigned short* __restrict__ Qb,
    const unsigned short* __restrict__ w2f,
    unsigned short* __restrict__ eBuf,
    int* __restrict__ cursor, int* __restrict__ lists,
    int b0, int period, int ebOff)
{
    __shared__ unsigned short hsh[4][64][64];  // 32 KB: wave-private slabs

    int bid = blockIdx.x;
    if (period) {
        int k = bid / period;
        int r = bid - k * period;
        if (r == period - 1) {
            // ---- CSR lists fill block k (k in [0, FILL_BLOCKS)) ----
            int e = k * 256 + threadIdx.x;
            if (e < E) {
                int p = atomicAdd(&cursor[eidx[E + e]], 1);
                lists[p] = e;
                int q = atomicAdd(&cursor[N + eidx[e]], 1);
                lists[q] = e;
            }
            return;
        }
        bid -= k;   // edge-block index among non-fill blocks
    }

    int t = bid * 256 + threadIdx.x;          // < nb*E
    int bb = t / E;
    int e = t - bb * E;
    int b = b0 + bb;
    int wv = threadIdx.x >> 6;
    int lane = threadIdx.x & 63;

    int src = eidx[e];
    int tgt = eidx[E + e];

    const uint4* Pr = (const uint4*)(Pb + ((size_t)b * N + src) * EH);  // 64 B
    const uint4* Qr = (const uint4*)(Qb + ((size_t)b * N + tgt) * EH);  // 64 B

    float h[EH];
    #pragma unroll
    for (int i = 0; i < 4; i++) {
        uint4 p = Pr[i];
        uint4 q = Qr[i];
        unsigned pu[4] = {p.x, p.y, p.z, p.w};
        unsigned qu[4] = {q.x, q.y, q.z, q.w};
        #pragma unroll
        for (int k2 = 0; k2 < 4; k2++) {
            float pl = __uint_as_float(pu[k2] << 16);
            float ph = __uint_as_float(pu[k2] & 0xFFFF0000u);
            float ql = __uint_as_float(qu[k2] << 16);
            float qh = __uint_as_float(qu[k2] & 0xFFFF0000u);
            h[8 * i + 2 * k2 + 0] = pl + ql;
            h[8 * i + 2 * k2 + 1] = ph + qh;
        }
    }

    float2 eav = *(const float2*)(ea + 2 * (size_t)e);
    float dist = eav.x, cdir = eav.y;
    float f32v = (dist - stats[4]) * stats[5];
    float f33v = (cdir - stats[6]) * stats[7];

    float2 xw = *(const float2*)(x + ((size_t)b * N + src) * D + 14);
    float speed = xw.x * wind_std[0] + wind_mean[0];
    float sdir  = xw.y * wind_std[1] + wind_mean[1];
    float ew = fmaxf(3.0f * speed * __cosf(fabsf(cdir - sdir)) *
                     __builtin_amdgcn_rcpf(dist), 0.0f);

    const float* W1r32 = W1 + 32 * EH;
    const float* W1r33 = W1 + 33 * EH;
    const float* W1r34 = W1 + 34 * EH;
    #pragma unroll
    for (int j = 0; j < EH; j++) {
        float v = h[j];
        v = fmaf(f32v, W1r32[j], v);
        v = fmaf(f33v, W1r33[j], v);
        v = fmaf(ew,   W1r34[j], v);
        h[j] = sigmoidf_(v);
    }

    // --- stage h as bf16 RNE (hi only), chunk-swizzled ---
    unsigned short* myrow = &hsh[wv][lane][0];
    int lx = lane & 7;
    #pragma unroll
    for (int i = 0; i < 4; i++) {
        unsigned hw[4];
        #pragma unroll
        for (int p = 0; p < 4; p++)
            hw[p] = pack_bf16_2(h[8 * i + 2 * p], h[8 * i + 2 * p + 1]);
        *(uint4*)(myrow + ((i ^ lx) << 3)) = make_uint4(hw[0], hw[1], hw[2], hw[3]);
    }
    LDS_FENCE();

    // --- B fragments (L1-hot, 4KB shared by all waves) ---
    union { uint4 u; bf16x8 v; } bf[4];
    const uint4* wfp = (const uint4*)w2f;
    #pragma unroll
    for (int i = 0; i < 4; i++) bf[i].u = wfp[i * 64 + lane];
    // bf[0]=tile0 hi, bf[1]=tile0 lo, bf[2]=tile1 hi, bf[3]=tile1 lo

    int m  = lane & 15;
    int hr = lane >> 4;
    float bias0 = b2[m];
    float bias1 = (m < EOUT - 16) ? b2[16 + m] : 0.0f;

    f32x4 acc[4][2];
    #pragma unroll
    for (int g = 0; g < 4; g++) {
        f32x4 z0 = {bias0, bias0, bias0, bias0};
        f32x4 z1 = {bias1, bias1, bias1, bias1};
        acc[g][0] = z0;
        acc[g][1] = z1;
    }

    int mx = m & 7;
    #pragma unroll
    for (int g = 0; g < 4; g++) {
        const unsigned short* rp = &hsh[wv][g * 16 + m][0];
        bf16x8 Ah = *(const bf16x8*)(rp + ((hr ^ mx) << 3));
        acc[g][0] = __builtin_amdgcn_mfma_f32_16x16x32_bf16(Ah, bf[0].v, acc[g][0], 0, 0, 0);
        acc[g][1] = __builtin_amdgcn_mfma_f32_16x16x32_bf16(Ah, bf[2].v, acc[g][1], 0, 0, 0);
        acc[g][0] = __builtin_amdgcn_mfma_f32_16x16x32_bf16(Ah, bf[1].v, acc[g][0], 0, 0, 0);
        acc[g][1] = __builtin_amdgcn_mfma_f32_16x16x32_bf16(Ah, bf[3].v, acc[g][1], 0, 0, 0);
    }
    LDS_FENCE();

    // --- epilogue: transpose C via LDS (staging data now dead) ---
    unsigned short* wb = &hsh[wv][0][0];   // 64 rows x 64 ush
    int c0 = m >> 3;
    int c1 = 2 + (m >> 3);
    int mp = m & 7;
    #pragma unroll
    for (int g = 0; g < 4; g++) {
        #pragma unroll
        for (int j = 0; j < 4; j++) {
            int er  = g * 16 + hr * 4 + j;
            int swz = ((hr & 1) << 2) | j;         // er & 7
            float v0 = sigmoidf_(acc[g][0][j]);
            float v1 = sigmoidf_(acc[g][1][j]);
            wb[er * 64 + ((c0 ^ swz) << 3) + mp] = bf16rn(v0);
            wb[er * 64 + ((c1 ^ swz) << 3) + mp] =
                (m < 14) ? bf16rn(v1) : (unsigned short)0;
        }
    }
    LDS_FENCE();

    // --- linear wave copy LDS -> eBuf (1KB contiguous per instruction) ---
    int eWaveBase = e - lane;
    int rrow = lane >> 2;
    int rx   = rrow & 7;
    unsigned short* wdst = eBuf + ((size_t)(b - ebOff) * E + eWaveBase) * EH;
    #pragma unroll
    for (int i = 0; i < 4; i++) {
        uint4 v = *(const uint4*)(wb + (i * 16 + rrow) * 64 + (((lane & 3) ^ rx) << 3));
        *(uint4*)(wdst + i * 512 + lane * 8) = v;
    }
}

// ---------------------------------------------------------------------------
// Gather + node MLP. One wave per (bb,node). (round-6 uint4 version,
// protocol-verified — unchanged; serial, after edge completes)
// ---------------------------------------------------------------------------
__global__ void __launch_bounds__(256) gather_kernel(
    const unsigned short* __restrict__ eBuf, const int* __restrict__ offs,
    const int* __restrict__ lists, const float* __restrict__ Wn,
    const float* __restrict__ bn, float* __restrict__ out,
    int b0, int nb, int ebOff)
{
    int wid = (blockIdx.x * blockDim.x + threadIdx.x) >> 6;
    int lane = threadIdx.x & 63;
    if (wid >= nb * N) return;
    int bb = wid / N;
    int node = wid - bb * N;
    int b = b0 + bb;

    int g = lane >> 2;       // row-group 0..15
    int c = lane & 3;        // uint4 index in row: covers cols 8c..8c+7
    const uint4* ebase = (const uint4*)(eBuf + (size_t)(b - ebOff) * E * EH);

    float a0 = 0.f, a1 = 0.f, a2 = 0.f, a3 = 0.f;
    float a4 = 0.f, a5 = 0.f, a6 = 0.f, a7 = 0.f;

    // in-list: add
    {
        int s = offs[node], e1 = offs[node + 1];
        for (int r = s; r < e1; r += 16) {
            int row = r + g;
            if (row < e1) {
                int eid = lists[row];
                uint4 v = ebase[(size_t)eid * 4 + c];
                a0 += __uint_as_float(v.x << 16);
                a1 += __uint_as_float(v.x & 0xFFFF0000u);
                a2 += __uint_as_float(v.y << 16);
                a3 += __uint_as_float(v.y & 0xFFFF0000u);
                a4 += __uint_as_float(v.z << 16);
                a5 += __uint_as_float(v.z & 0xFFFF0000u);
                a6 += __uint_as_float(v.w << 16);
                a7 += __uint_as_float(v.w & 0xFFFF0000u);
            }
        }
    }
    // out-list: subtract
    {
        int s = offs[N + node], e1 = offs[N + node + 1];
        for (int r = s; r < e1; r += 16) {
            int row = r + g;
            if (row < e1) {
                int eid = lists[row];
                uint4 v = ebase[(size_t)eid * 4 + c];
                a0 -= __uint_as_float(v.x << 16);
                a1 -= __uint_as_float(v.x & 0xFFFF0000u);
                a2 -= __uint_as_float(v.y << 16);
                a3 -= __uint_as_float(v.y & 0xFFFF0000u);
                a4 -= __uint_as_float(v.z << 16);
                a5 -= __uint_as_float(v.z & 0xFFFF0000u);
                a6 -= __uint_as_float(v.w << 16);
                a7 -= __uint_as_float(v.w & 0xFFFF0000u);
            }
        }
    }

    // fold the 16 row-groups: lanes sharing (lane&3) end with full column sums
    #pragma unroll
    for (int off = 4; off <= 32; off <<= 1) {
        a0 += __shfl_xor(a0, off); a1 += __shfl_xor(a1, off);
        a2 += __shfl_xor(a2, off); a3 += __shfl_xor(a3, off);
        a4 += __shfl_xor(a4, off); a5 += __shfl_xor(a5, off);
        a6 += __shfl_xor(a6, off); a7 += __shfl_xor(a7, off);
    }

    // node layer: agg col k lives in slot (k&7) of lane (k>>3)
    float o = bn[lane];
    #pragma unroll
    for (int k = 0; k < EOUT; k++) {
        float av;
        switch (k & 7) {
            case 0:  av = a0; break;
            case 1:  av = a1; break;
            case 2:  av = a2; break;
            case 3:  av = a3; break;
            case 4:  av = a4; break;
            case 5:  av = a5; break;
            case 6:  av = a6; break;
            default: av = a7; break;
        }
        float ak = __shfl(av, k >> 3);
        o = fmaf(ak, Wn[k * NOUT + lane], o);
    }
    out[((size_t)b * N + node) * NOUT + lane] = sigmoidf_(o);
}

// ---------------------------------------------------------------------------
// Fallback (small ws): atomic path
// ---------------------------------------------------------------------------
__global__ void __launch_bounds__(256) edge_kernel_atomic(
    const float* __restrict__ x, const int* __restrict__ eidx,
    const float* __restrict__ ea,
    const float* __restrict__ wind_mean, const float* __restrict__ wind_std,
    const float* __restrict__ W1, const float* __restrict__ b1,
    const float* __restrict__ W2, const float* __restrict__ b2,
    const float* __restrict__ stats, float* __restrict__ agg)
{
    int t = blockIdx.x * blockDim.x + threadIdx.x;
    if (t >= B * E) return;
    int b = t / E;
    int e = t - b * E;
    int src = eidx[e];
    int tgt = eidx[E + e];
    const float* xs = x + ((size_t)b * N + src) * D;
    const float* xt = x + ((size_t)b * N + tgt) * D;
    float f[FEAT];
    #pragma unroll
    for (int i = 0; i < D; i++) f[i] = xs[i];
    #pragma unroll
    for (int i = 0; i < D; i++) f[D + i] = xt[i];
    float2 eav = *(const float2*)(ea + 2 * (size_t)e);
    f[32] = (eav.x - stats[4]) * stats[5];
    f[33] = (eav.y - stats[6]) * stats[7];
    float speed = f[14] * wind_std[0] + wind_mean[0];
    float sdir  = f[15] * wind_std[1] + wind_mean[1];
    f[34] = fmaxf(3.0f * speed * cosf(fabsf(eav.y - sdir)) / eav.x, 0.0f);
    float h[EH];
    #pragma unroll
    for (int j = 0; j < EH; j++) h[j] = b1[j];
    #pragma unroll
    for (int k = 0; k < FEAT; k++) {
        float fk = f[k];
        #pragma unroll
        for (int j = 0; j < EH; j++) h[j] = fmaf(fk, W1[k * EH + j], h[j]);
    }
    #pragma unroll
    for (int j = 0; j < EH; j++) h[j] = sigmoidf_(h[j]);
    float o[EOUT];
    #pragma unroll
    for (int j = 0; j < EOUT; j++) o[j] = b2[j];
    #pragma unroll
    for (int k = 0; k < EH; k++) {
        float hk = h[k];
        #pragma unroll
        for (int j = 0; j < EOUT; j++) o[j] = fmaf(hk, W2[k * EOUT + j], o[j]);
    }
    float* at = agg + ((size_t)b * N + tgt) * EOUT;
    float* as = agg + ((size_t)b * N + src) * EOUT;
    #pragma unroll
    for (int j = 0; j < EOUT; j++) {
        float v = sigmoidf_(o[j]);
        atomicAdd(at + j,  v);
        atomicAdd(as + j, -v);
    }
}

__global__ void __launch_bounds__(256) node_kernel_fallback(
    const float* __restrict__ agg, const float* __restrict__ Wn,
    const float* __restrict__ bn, float* __restrict__ out)
{
    int t = blockIdx.x * blockDim.x + threadIdx.x;
    if (t >= B * N * NOUT) return;
    int row = t >> 6;
    int j   = t & 63;
    const float* a = agg + (size_t)row * EOUT;
    float acc = bn[j];
    #pragma unroll
    for (int k = 0; k < EOUT; k++) acc = fmaf(a[k], Wn[k * NOUT + j], acc);
    out[t] = sigmoidf_(acc);
}

// ---------------------------------------------------------------------------
extern "C" void kernel_launch(void* const* d_in, const int* in_sizes, int n_in,
                              void* d_out, int out_size, void* d_ws, size_t ws_size,
                              hipStream_t stream) {
    const float* x         = (const float*)d_in[0];
    const int*   eidx      = (const int*)d_in[1];
    const float* ea        = (const float*)d_in[2];
    const float* wind_mean = (const float*)d_in[3];
    const float* wind_std  = (const float*)d_in[4];
    const float* W1        = (const float*)d_in[5];
    const float* b1        = (const float*)d_in[6];
    const float* W2        = (const float*)d_in[7];
    const float* b2        = (const float*)d_in[8];
    const float* Wn        = (const float*)d_in[9];
    const float* bn        = (const float*)d_in[10];
    float* out = (float*)d_out;

    char* ws = (char*)d_ws;
    // layout:
    //   stats [0,256) | w2f [256,4352) | offs [4352,84480) | cnt/cursor [84480,164608)
    //   lists [164608,2724608)
    //   P(bf16) [2724608,7844608) | Q(bf16) [7844608,12964608) | eBuf [12964608,...)
    float*          stats = (float*)(ws + 0);
    unsigned short* w2f   = (unsigned short*)(ws + 256);
    int*            offs  = (int*)(ws + 4352);
    int*            cnt   = (int*)(ws + 84480);
    int*            lists = (int*)(ws + 164608);
    unsigned short* Pb    = (unsigned short*)(ws + 2724608);
    unsigned short* Qb    = (unsigned short*)(ws + 7844608);
    unsigned short* eBuf  = (unsigned short*)(ws + 12964608);
    const size_t fixed = 12964608;
    const size_t perBatch = (size_t)E * EH * sizeof(unsigned short); // 20,480,000

    if (ws_size >= fixed + perBatch) {
        int chunk = (int)((ws_size - fixed) / perBatch);
        if (chunk > 8) chunk = 8;   // eBuf up to 164 MB -> still L3-resident

        hipMemsetAsync(ws, 0, 164608, stream);

        stats_count_kernel<<<256, 256, 0, stream>>>(ea, eidx, stats, cnt);
        scan_pq_kernel<<<1 + PQ1K_BLOCKS, 1024, 0, stream>>>(
            cnt, offs, cnt, stats, W2, w2f, x, W1, b1, Pb, Qb);

        for (int b0 = 0; b0 < B; b0 += chunk) {
            int nb = B - b0; if (nb > chunk) nb = chunk;
            int eblk = nb * E / 256;                     // E%256==0, = nb*1250
            int period = (b0 == 0) ? (nb + 1) : 0;       // 1 fill block / period
            int grid = eblk + ((b0 == 0) ? FILL_BLOCKS : 0);
            edge_mlp_kernel<<<grid, 256, 0, stream>>>(
                x, eidx, ea, wind_mean, wind_std, W1, b2, stats,
                Pb, Qb, w2f, eBuf, cnt, lists, b0, period, /*ebOff=*/b0);
            gather_kernel<<<nb * (N * 64 / 256), 256, 0, stream>>>(
                eBuf, offs, lists, Wn, bn, out, b0, nb, /*ebOff=*/b0);
        }
    } else {
        float* agg = (float*)(ws + 164608);
        size_t zero_bytes = 164608 + (size_t)B * N * EOUT * sizeof(float);
        hipMemsetAsync(ws, 0, zero_bytes, stream);
        stats_count_kernel<<<256, 256, 0, stream>>>(ea, eidx, stats, cnt);
        scan_pq_kernel<<<1, 1024, 0, stream>>>(
            cnt, offs, cnt, stats, W2, w2f, x, W1, b1,
            (unsigned short*)(ws + 256), (unsigned short*)(ws + 256));  // grid=1: PQ unused
        int nwork = B * E;
        edge_kernel_atomic<<<(nwork + 255) / 256, 256, 0, stream>>>(
            x, eidx, ea, wind_mean, wind_std, W1, b1, W2, b2, stats, agg);
        int nout_elems = B * N * NOUT;
        node_kernel_fallback<<<(nout_elems + 255) / 256, 256, 0, stream>>>(
            agg, Wn, bn, out);
    }
}